// Round 1
// baseline (2036.124 us; speedup 1.0000x reference)
//
#include <hip/hip_runtime.h>
#include <math.h>

// Problem constants (fixed by the reference)
constexpr int B_   = 16;
constexpr int DIM  = 1024;
constexpr int T_   = 2048;
constexpr int NFFT = 1024;
constexpr int HOP  = 256;
constexpr int NBINS = 513;          // NFFT/2+1
constexpr int M_TOT = B_ * T_;      // 32768 rows
constexpr int N_HEAD = 2 * NBINS;   // 1026 (logmag || instfreq)
constexpr int OUT_LEN = HOP * (T_ - 1);   // 524032 per batch
constexpr float TWO_PI_F = 6.28318530717958647692f;
constexpr float PI_F = 3.14159265358979323846f;

// ---------------------------------------------------------------------------
// K0: precompute iDFT basis with irfft weights + Hann window folded in.
// basis[n][j], n in [0,1026): n<513 -> cos row k=n  (weight 1 for k=0,512, else 2)
//                             n>=513 -> -sin row k=n-513 (weight 0 for k=0,512, else 2)
// all scaled by 1/NFFT and multiplied by periodic Hann win[j].
// ---------------------------------------------------------------------------
__global__ void k_basis(float* __restrict__ basis) {
    int idx = blockIdx.x * 256 + threadIdx.x;
    if (idx >= N_HEAD * NFFT) return;
    int n = idx >> 10;          // / NFFT
    int j = idx & (NFFT - 1);
    float win = 0.5f * (1.0f - __cosf((float)j * (TWO_PI_F / NFFT)));
    int k = (n < NBINS) ? n : (n - NBINS);
    int r = (k * j) & (NFFT - 1);           // exact angle reduction (integer)
    float ang = (float)r * (TWO_PI_F / NFFT);
    float s, c;
    __sincosf(ang, &s, &c);
    float v;
    if (n < NBINS) {
        float w = (k == 0 || k == NFFT / 2) ? 1.0f : 2.0f;
        v = (w / (float)NFFT) * c;
    } else {
        float w = (k == 0 || k == NFFT / 2) ? 0.0f : 2.0f;  // imag of DC/Nyquist ignored
        v = -(w / (float)NFFT) * s;
    }
    basis[idx] = v * win;
}

// ---------------------------------------------------------------------------
// K1: dual head GEMM.  out[n][m] = clip( sum_k x[b,k,t] * Wc[n,k] + bias[n] )
//   m = b*T + t ; A is x (K-major: contiguous along m within a batch)
//   n<513: W_mag row n, clip +-10 ; n>=513: W_phase row n-513, clip +-pi
// Tiles: 128(M) x 128(N) x 16(K), 256 threads, 8x8 micro-tile.
// Output stored transposed [N_HEAD][M_TOT] so stage 2 scans contiguous rows.
// ---------------------------------------------------------------------------
constexpr int MT = 128, NT = 128, KT = 16;

__global__ __launch_bounds__(256) void k_head_gemm(
    const float* __restrict__ x, const float* __restrict__ Wm,
    const float* __restrict__ bm, const float* __restrict__ Wp,
    const float* __restrict__ bp, float* __restrict__ out) {
    __shared__ float As[KT][MT];        // [k][m]
    __shared__ float Bs[KT][NT + 4];    // [k][n], padded stride 132

    const int n0 = blockIdx.x * NT;     // 9 blocks -> covers 1152, guarded
    const int m0 = blockIdx.y * MT;     // 256 blocks
    const int tid = threadIdx.x;
    const int tx = tid & 15;            // along m
    const int ty = tid >> 4;            // along n
    const int b = m0 >> 11;             // / T_
    const int t0 = m0 & (T_ - 1);
    const float* xb = x + (size_t)b * DIM * T_ + t0;

    float acc[8][8];                    // [nj][mi]
#pragma unroll
    for (int i = 0; i < 8; ++i)
#pragma unroll
        for (int j = 0; j < 8; ++j) acc[i][j] = 0.0f;

    for (int k0 = 0; k0 < DIM; k0 += KT) {
        // stage A tile: 16 x 128 floats = 512 float4, 2 per thread
#pragma unroll
        for (int r = 0; r < 2; ++r) {
            int l = tid + r * 256;
            int kk = l >> 5;
            int mm = (l & 31) << 2;
            float4 v = *(const float4*)(xb + (size_t)(k0 + kk) * T_ + mm);
            *(float4*)(&As[kk][mm]) = v;
        }
        // stage B tile (transpose W rows into [k][n])
#pragma unroll
        for (int r = 0; r < 2; ++r) {
            int l = tid + r * 256;
            int nn = l >> 2;            // 0..127
            int kc = (l & 3) << 2;      // 0,4,8,12
            int n = n0 + nn;
            float4 v = make_float4(0.f, 0.f, 0.f, 0.f);
            if (n < N_HEAD) {
                const float* Wrow = (n < NBINS) ? (Wm + (size_t)n * DIM)
                                                : (Wp + (size_t)(n - NBINS) * DIM);
                v = *(const float4*)(Wrow + k0 + kc);
            }
            Bs[kc + 0][nn] = v.x;
            Bs[kc + 1][nn] = v.y;
            Bs[kc + 2][nn] = v.z;
            Bs[kc + 3][nn] = v.w;
        }
        __syncthreads();
#pragma unroll
        for (int kt = 0; kt < KT; ++kt) {
            float a[8], bb[8];
            *(float4*)&a[0] = *(float4*)&As[kt][tx * 8];
            *(float4*)&a[4] = *(float4*)&As[kt][tx * 8 + 4];
            *(float4*)&bb[0] = *(float4*)&Bs[kt][ty * 8];
            *(float4*)&bb[4] = *(float4*)&Bs[kt][ty * 8 + 4];
#pragma unroll
            for (int nj = 0; nj < 8; ++nj)
#pragma unroll
                for (int mi = 0; mi < 8; ++mi) acc[nj][mi] += bb[nj] * a[mi];
        }
        __syncthreads();
    }

    // epilogue: bias + clip, store transposed [n][m]
#pragma unroll
    for (int nj = 0; nj < 8; ++nj) {
        int n = n0 + ty * 8 + nj;
        if (n >= N_HEAD) continue;
        float bias, hi;
        if (n < NBINS) { bias = bm[n]; hi = 10.0f; }
        else           { bias = bp[n - NBINS]; hi = PI_F; }
        float lo = -hi;
        float v[8];
#pragma unroll
        for (int mi = 0; mi < 8; ++mi)
            v[mi] = fminf(fmaxf(acc[nj][mi] + bias, lo), hi);
        size_t o = (size_t)n * M_TOT + m0 + tx * 8;
        *(float4*)(out + o)     = *(float4*)&v[0];
        *(float4*)(out + o + 4) = *(float4*)&v[4];
    }
}

// ---------------------------------------------------------------------------
// K2: per (b,k): cumsum inst_freq over t (block scan of 2048), then
//     a = exp(logmag)*cos(phase), bIm = exp(logmag)*sin(phase), in place.
// ---------------------------------------------------------------------------
__global__ __launch_bounds__(256) void k_scan(float* __restrict__ buf) {
    const int k = blockIdx.x;       // 0..512
    const int b = blockIdx.y;       // 0..15
    const int tid = threadIdx.x;
    float* lmrow = buf + (size_t)k * M_TOT + b * T_;
    float* ifrow = buf + (size_t)(NBINS + k) * M_TOT + b * T_;

    float v[8];
    float4 u0 = *(float4*)(ifrow + tid * 8);
    float4 u1 = *(float4*)(ifrow + tid * 8 + 4);
    v[0] = u0.x; v[1] = u0.y; v[2] = u0.z; v[3] = u0.w;
    v[4] = u1.x; v[5] = u1.y; v[6] = u1.z; v[7] = u1.w;

    float run = 0.0f;
#pragma unroll
    for (int i = 0; i < 8; ++i) { run += v[i]; v[i] = run; }   // inclusive in-thread
    const float total = run;

    __shared__ float sd[256];
    sd[tid] = total;
    __syncthreads();
    for (int off = 1; off < 256; off <<= 1) {
        float t = (tid >= off) ? sd[tid - off] : 0.0f;
        __syncthreads();
        sd[tid] += t;
        __syncthreads();
    }
    const float excl = sd[tid] - total;

    float lm[8];
    float4 w0 = *(float4*)(lmrow + tid * 8);
    float4 w1 = *(float4*)(lmrow + tid * 8 + 4);
    lm[0] = w0.x; lm[1] = w0.y; lm[2] = w0.z; lm[3] = w0.w;
    lm[4] = w1.x; lm[5] = w1.y; lm[6] = w1.z; lm[7] = w1.w;

    float ar[8], br[8];
#pragma unroll
    for (int i = 0; i < 8; ++i) {
        float phase = excl + v[i];
        float mag = expf(lm[i]);
        float s, c;
        sincosf(phase, &s, &c);      // accurate: phase can be O(100)
        ar[i] = mag * c;
        br[i] = mag * s;
    }
    *(float4*)(lmrow + tid * 8)     = *(float4*)&ar[0];
    *(float4*)(lmrow + tid * 8 + 4) = *(float4*)&ar[4];
    *(float4*)(ifrow + tid * 8)     = *(float4*)&br[0];
    *(float4*)(ifrow + tid * 8 + 4) = *(float4*)&br[4];
}

// ---------------------------------------------------------------------------
// K3: iDFT-as-GEMM.  frames[m][j] = sum_n ab[n][m] * basis[n][j]
// Same tiling as K1; K = 1026 (last iter partial, zero-filled).
// Window already folded into basis.
// ---------------------------------------------------------------------------
__global__ __launch_bounds__(256) void k_idft_gemm(
    const float* __restrict__ ab, const float* __restrict__ basis,
    float* __restrict__ frames) {
    __shared__ float As[KT][MT];        // [n][m]
    __shared__ float Bs[KT][NT + 4];    // [n][j]

    const int j0 = blockIdx.x * NT;     // 8 blocks
    const int m0 = blockIdx.y * MT;     // 256 blocks
    const int tid = threadIdx.x;
    const int tx = tid & 15;            // along j
    const int ty = tid >> 4;            // along m

    float acc[8][8];                    // [mi][ji]
#pragma unroll
    for (int i = 0; i < 8; ++i)
#pragma unroll
        for (int j = 0; j < 8; ++j) acc[i][j] = 0.0f;

    for (int k0 = 0; k0 < N_HEAD; k0 += KT) {
#pragma unroll
        for (int r = 0; r < 2; ++r) {
            int l = tid + r * 256;
            int kk = l >> 5;
            int mm = (l & 31) << 2;
            int n = k0 + kk;
            float4 v = make_float4(0.f, 0.f, 0.f, 0.f);
            if (n < N_HEAD) v = *(const float4*)(ab + (size_t)n * M_TOT + m0 + mm);
            *(float4*)(&As[kk][mm]) = v;
        }
#pragma unroll
        for (int r = 0; r < 2; ++r) {
            int l = tid + r * 256;
            int kk = l >> 5;
            int jj = (l & 31) << 2;
            int n = k0 + kk;
            float4 v = make_float4(0.f, 0.f, 0.f, 0.f);
            if (n < N_HEAD) v = *(const float4*)(basis + (size_t)n * NFFT + j0 + jj);
            *(float4*)(&Bs[kk][jj]) = v;
        }
        __syncthreads();
#pragma unroll
        for (int kt = 0; kt < KT; ++kt) {
            float a[8], bb[8];
            *(float4*)&a[0] = *(float4*)&As[kt][ty * 8];
            *(float4*)&a[4] = *(float4*)&As[kt][ty * 8 + 4];
            *(float4*)&bb[0] = *(float4*)&Bs[kt][tx * 8];
            *(float4*)&bb[4] = *(float4*)&Bs[kt][tx * 8 + 4];
#pragma unroll
            for (int mi = 0; mi < 8; ++mi)
#pragma unroll
                for (int ji = 0; ji < 8; ++ji) acc[mi][ji] += a[mi] * bb[ji];
        }
        __syncthreads();
    }

#pragma unroll
    for (int mi = 0; mi < 8; ++mi) {
        size_t row = (size_t)(m0 + ty * 8 + mi) * NFFT + j0 + tx * 8;
        *(float4*)(frames + row)     = *(float4*)&acc[mi][0];
        *(float4*)(frames + row + 4) = *(float4*)&acc[mi][4];
    }
}

// ---------------------------------------------------------------------------
// K4: overlap-add gather + envelope divide + clip.
// audio[b][s_out] ; s = s_out + NFFT/2 ; frames windowed already.
// ---------------------------------------------------------------------------
__global__ void k_ola(const float* __restrict__ frames, float* __restrict__ out) {
    const int s_out = blockIdx.x * 256 + threadIdx.x;   // 2047 blocks * 256 == OUT_LEN
    const int b = blockIdx.y;
    const int s = s_out + NFFT / 2;
    int t_lo = (s - (NFFT - HOP)) >> 8;                 // floor((s-768)/256)
    if (t_lo < 0) t_lo = 0;
    int t_hi = s >> 8;
    if (t_hi > T_ - 1) t_hi = T_ - 1;
    float acc = 0.0f, env = 0.0f;
    for (int t = t_lo; t <= t_hi; ++t) {
        int j = s - (t << 8);
        acc += frames[((size_t)(b * T_ + t) << 10) + j];
        float w = 0.5f * (1.0f - __cosf((float)j * (TWO_PI_F / NFFT)));
        env += w * w;
    }
    float r = acc / env;
    r = fminf(fmaxf(r, -1.0f), 1.0f);
    out[(size_t)b * OUT_LEN + s_out] = r;
}

// ---------------------------------------------------------------------------
extern "C" void kernel_launch(void* const* d_in, const int* in_sizes, int n_in,
                              void* d_out, int out_size, void* d_ws, size_t ws_size,
                              hipStream_t stream) {
    const float* x  = (const float*)d_in[0];
    const float* Wm = (const float*)d_in[1];
    const float* bm = (const float*)d_in[2];
    const float* Wp = (const float*)d_in[3];
    const float* bp = (const float*)d_in[4];
    float* out = (float*)d_out;

    char* ws = (char*)d_ws;
    float* buf0   = (float*)ws;                                   // [1026][32768] f32
    size_t buf0_b = (size_t)N_HEAD * M_TOT * sizeof(float);       // 134,479,872 B
    float* frames = (float*)(ws + buf0_b);                        // [32768][1024] f32
    size_t fr_b   = (size_t)M_TOT * NFFT * sizeof(float);         // 134,217,728 B
    float* basis  = (float*)(ws + buf0_b + fr_b);                 // [1026][1024] f32

    k_basis<<<dim3((N_HEAD * NFFT + 255) / 256), 256, 0, stream>>>(basis);
    k_head_gemm<<<dim3((N_HEAD + NT - 1) / NT, M_TOT / MT), 256, 0, stream>>>(
        x, Wm, bm, Wp, bp, buf0);
    k_scan<<<dim3(NBINS, B_), 256, 0, stream>>>(buf0);
    k_idft_gemm<<<dim3(NFFT / NT, M_TOT / MT), 256, 0, stream>>>(buf0, basis, frames);
    k_ola<<<dim3(OUT_LEN / 256, B_), 256, 0, stream>>>(frames, out);
}

// Round 2
// 798.800 us; speedup vs baseline: 2.5490x; 2.5490x over previous
//
#include <hip/hip_runtime.h>
#include <math.h>

// Problem constants
constexpr int B_   = 16;
constexpr int DIM  = 1024;
constexpr int T_   = 2048;
constexpr int NFFT = 1024;
constexpr int HOP  = 256;
constexpr int NBINS = 513;
constexpr int M_TOT = B_ * T_;            // 32768
constexpr int OUT_LEN = HOP * (T_ - 1);   // 524032
constexpr int NPAD = 640;                 // padded rows per head region
constexpr int NROWS = 2 * NPAD;           // 1280 packed W rows
constexpr int KSPEC = 1056;               // spec/basis K (513 cos + 15 pad + 512 sin + 16 pad)
constexpr float TWO_PI_F = 6.28318530717958647692f;
constexpr float PI_F = 3.14159265358979323846f;

typedef _Float16 h8 __attribute__((ext_vector_type(8)));
typedef float f4 __attribute__((ext_vector_type(4)));

#define GLOAD_LDS16(g, l) __builtin_amdgcn_global_load_lds(                  \
    (const __attribute__((address_space(1))) void*)(g),                      \
    (__attribute__((address_space(3))) void*)(l), 16, 0, 0)

// ---------------------------------------------------------------------------
// Convert x [b][k][t] f32 -> xT hi/lo [b][t][k] f16 (64x64 tile transpose)
// ---------------------------------------------------------------------------
__global__ __launch_bounds__(256) void k_convert_x(
    const float* __restrict__ x, _Float16* __restrict__ xh, _Float16* __restrict__ xl) {
    __shared__ float tile[64][65];
    const int tid = threadIdx.x;
    const int k0 = blockIdx.x * 64;
    const int t0 = blockIdx.y * 64;
    const int b  = blockIdx.z;
    {
        int kr = tid >> 2;
        int tq = (tid & 3) * 16;
        const float* src = x + ((size_t)(b * DIM + k0 + kr)) * T_ + t0 + tq;
        #pragma unroll
        for (int i = 0; i < 4; ++i) {
            float4 v = *(const float4*)(src + i * 4);
            tile[kr][tq + i * 4 + 0] = v.x;
            tile[kr][tq + i * 4 + 1] = v.y;
            tile[kr][tq + i * 4 + 2] = v.z;
            tile[kr][tq + i * 4 + 3] = v.w;
        }
    }
    __syncthreads();
    {
        int tr = tid >> 2;
        int kq = (tid & 3) * 16;
        _Float16 hv[16], lv[16];
        #pragma unroll
        for (int i = 0; i < 16; ++i) {
            float w = tile[kq + i][tr];
            _Float16 h = (_Float16)w;
            hv[i] = h;
            lv[i] = (_Float16)(w - (float)h);
        }
        size_t base = ((size_t)(b * T_ + t0 + tr)) * DIM + k0 + kq;
        *(h8*)(xh + base)     = *(const h8*)&hv[0];
        *(h8*)(xh + base + 8) = *(const h8*)&hv[8];
        *(h8*)(xl + base)     = *(const h8*)&lv[0];
        *(h8*)(xl + base + 8) = *(const h8*)&lv[8];
    }
}

// ---------------------------------------------------------------------------
// Pack W: rows 0..512 = W_mag, 513..639 zero, 640..1152 = W_phase, rest zero
// ---------------------------------------------------------------------------
__global__ void k_pack_w(const float* __restrict__ Wm, const float* __restrict__ Wp,
                         _Float16* __restrict__ Wh, _Float16* __restrict__ Wl) {
    int idx = blockIdx.x * 256 + threadIdx.x;
    if (idx >= NROWS * DIM) return;
    int n = idx >> 10, k = idx & 1023;
    float w = 0.f;
    if (n < NBINS) w = Wm[(size_t)n * DIM + k];
    else if (n >= NPAD && n < NPAD + NBINS) w = Wp[(size_t)(n - NPAD) * DIM + k];
    _Float16 h = (_Float16)w;
    Wh[idx] = h;
    Wl[idx] = (_Float16)(w - (float)h);
}

__global__ void k_pack_bias(const float* __restrict__ bm, const float* __restrict__ bp,
                            float* __restrict__ biasp) {
    int n = blockIdx.x * 256 + threadIdx.x;
    if (n >= NROWS) return;
    float v = 0.f;
    if (n < NBINS) v = bm[n];
    else if (n >= NPAD && n < NPAD + NBINS) v = bp[n - NPAD];
    biasp[n] = v;
}

// ---------------------------------------------------------------------------
// basisT[j][r] f16, stride KSPEC. r<513: cos bin k=r (w=1 for k=0,512 else 2);
// 528<=r<1040: -sin bin k=r-528 (w=2; k=0 row is 0 anyway). Pads are ZERO.
// Includes 1/N and Hann window.
// ---------------------------------------------------------------------------
__global__ void k_basisT(_Float16* __restrict__ basisT) {
    int idx = blockIdx.x * 256 + threadIdx.x;
    if (idx >= NFFT * KSPEC) return;
    int j = idx / KSPEC;
    int r = idx - j * KSPEC;
    float win = 0.5f * (1.0f - __cosf((float)j * (TWO_PI_F / NFFT)));
    float val = 0.f;
    if (r < NBINS) {
        int k = r;
        int m = (k * j) & (NFFT - 1);
        float s, c;
        __sincosf((float)m * (TWO_PI_F / NFFT), &s, &c);
        float w = (k == 0 || k == NFFT / 2) ? 1.0f : 2.0f;
        val = w * (1.0f / NFFT) * c * win;
    } else if (r >= 528 && r < 1040) {
        int k = r - 528;
        int m = (k * j) & (NFFT - 1);
        float s, c;
        __sincosf((float)m * (TWO_PI_F / NFFT), &s, &c);
        val = -2.0f * (1.0f / NFFT) * s * win;
    }
    basisT[idx] = (_Float16)val;
}

// ---------------------------------------------------------------------------
// GEMM1 (heads): D[n][m] = sum_k Wpack[n][k] * x[b][k][t].
// A = Wpack (f16 hi/lo), B = xT (f16 hi/lo). 128x128 tile, BK=32, 4 waves.
// Mag blocks (n0<640): 1-pass hi*hi, epilogue exp(clip(.)) -> f16.
// Phase blocks: 3-pass (hi*hi + hi*lo + lo*hi), epilogue clip -> f32.
// ---------------------------------------------------------------------------
__global__ __launch_bounds__(256) void k_gemm_head(
    const _Float16* __restrict__ Wh, const _Float16* __restrict__ Wl,
    const _Float16* __restrict__ xh, const _Float16* __restrict__ xl,
    const float* __restrict__ biasp,
    _Float16* __restrict__ bufmag, float* __restrict__ bufph) {
    __shared__ _Float16 sA[2][128 * 32];
    __shared__ _Float16 sB[2][128 * 32];
    const int tid = threadIdx.x;
    const int lane = tid & 63;
    const int wv = tid >> 6;
    const int wr = wv >> 1, wc = wv & 1;
    const int quad = lane >> 4, l16 = lane & 15;
    const int n0 = blockIdx.x * 128;
    const int m0 = blockIdx.y * 128;
    const bool ph = (n0 >= NPAD);
    const int b = m0 >> 11;
    const int t0 = m0 & (T_ - 1);
    const size_t xbase = ((size_t)(b * T_ + t0)) * DIM;

    const int cid0 = wv * 128 + lane;
    const int cid1 = cid0 + 64;
    const int ar0 = cid0 >> 2, aq0 = cid0 & 3;
    const int ar1 = cid1 >> 2, aq1 = cid1 & 3;

    f4 acc[4][4];
    f4 zero = {0.f, 0.f, 0.f, 0.f};
    #pragma unroll
    for (int i = 0; i < 4; ++i)
        #pragma unroll
        for (int j = 0; j < 4; ++j) acc[i][j] = zero;

    for (int k0 = 0; k0 < DIM; k0 += 32) {
        _Float16* dA = &sA[0][wv * 128 * 8];
        _Float16* dB = &sB[0][wv * 128 * 8];
        GLOAD_LDS16(Wh + ((size_t)(n0 + ar0) << 10) + k0 + aq0 * 8, dA);
        GLOAD_LDS16(Wh + ((size_t)(n0 + ar1) << 10) + k0 + aq1 * 8, dA + 512);
        GLOAD_LDS16(xh + xbase + ((size_t)ar0 << 10) + k0 + aq0 * 8, dB);
        GLOAD_LDS16(xh + xbase + ((size_t)ar1 << 10) + k0 + aq1 * 8, dB + 512);
        if (ph) {
            _Float16* dAl = &sA[1][wv * 128 * 8];
            _Float16* dBl = &sB[1][wv * 128 * 8];
            GLOAD_LDS16(Wl + ((size_t)(n0 + ar0) << 10) + k0 + aq0 * 8, dAl);
            GLOAD_LDS16(Wl + ((size_t)(n0 + ar1) << 10) + k0 + aq1 * 8, dAl + 512);
            GLOAD_LDS16(xl + xbase + ((size_t)ar0 << 10) + k0 + aq0 * 8, dBl);
            GLOAD_LDS16(xl + xbase + ((size_t)ar1 << 10) + k0 + aq1 * 8, dBl + 512);
        }
        __syncthreads();

        h8 aH[4], bH[4], aL[4], bL[4];
        #pragma unroll
        for (int rt = 0; rt < 4; ++rt) {
            int row = wr * 64 + rt * 16 + l16;
            aH[rt] = *(const h8*)&sA[0][row * 32 + quad * 8];
        }
        #pragma unroll
        for (int ct = 0; ct < 4; ++ct) {
            int col = wc * 64 + ct * 16 + l16;
            bH[ct] = *(const h8*)&sB[0][col * 32 + quad * 8];
        }
        if (ph) {
            #pragma unroll
            for (int rt = 0; rt < 4; ++rt) {
                int row = wr * 64 + rt * 16 + l16;
                aL[rt] = *(const h8*)&sA[1][row * 32 + quad * 8];
            }
            #pragma unroll
            for (int ct = 0; ct < 4; ++ct) {
                int col = wc * 64 + ct * 16 + l16;
                bL[ct] = *(const h8*)&sB[1][col * 32 + quad * 8];
            }
        }
        #pragma unroll
        for (int rt = 0; rt < 4; ++rt)
            #pragma unroll
            for (int ct = 0; ct < 4; ++ct) {
                acc[rt][ct] = __builtin_amdgcn_mfma_f32_16x16x32_f16(aH[rt], bH[ct], acc[rt][ct], 0, 0, 0);
                if (ph) {
                    acc[rt][ct] = __builtin_amdgcn_mfma_f32_16x16x32_f16(aH[rt], bL[ct], acc[rt][ct], 0, 0, 0);
                    acc[rt][ct] = __builtin_amdgcn_mfma_f32_16x16x32_f16(aL[rt], bH[ct], acc[rt][ct], 0, 0, 0);
                }
            }
        __syncthreads();
    }

    #pragma unroll
    for (int rt = 0; rt < 4; ++rt) {
        int nbase = n0 + wr * 64 + rt * 16 + quad * 4;
        #pragma unroll
        for (int ct = 0; ct < 4; ++ct) {
            int col = m0 + wc * 64 + ct * 16 + l16;
            f4 v = acc[rt][ct];
            #pragma unroll
            for (int r = 0; r < 4; ++r) {
                int n = nbase + r;
                float val = v[r] + biasp[n];
                if (!ph) {
                    val = fminf(fmaxf(val, -10.f), 10.f);
                    bufmag[(size_t)n * M_TOT + col] = (_Float16)expf(val);
                } else {
                    val = fminf(fmaxf(val, -PI_F), PI_F);
                    bufph[(size_t)(n - NPAD) * M_TOT + col] = val;
                }
            }
        }
    }
}

// ---------------------------------------------------------------------------
// Scan: per (k-tile of 32, b): cumsum inst_freq over t, spec = mag*e^{i phase},
// written TRANSPOSED to specT[m][KSPEC] f16: cos part -> col k, sin part ->
// col 528+k. kt==16 (k=512): only col 512 written.
// ---------------------------------------------------------------------------
__global__ __launch_bounds__(256) void k_scan(
    const _Float16* __restrict__ mag, const float* __restrict__ iF,
    _Float16* __restrict__ specT) {
    __shared__ float sums[32][65];
    __shared__ _Float16 ta[256][32];
    __shared__ _Float16 tb[256][32];
    const int tid = threadIdx.x;
    const int r = tid & 31;
    const int sg = tid >> 5;        // 0..7
    const int kt = blockIdx.x;      // 0..16
    const int b = blockIdx.y;
    const int k = kt * 32 + r;      // rows up to 543 exist (pad rows are clean zeros)
    const size_t base = (size_t)k * M_TOT + b * T_;

    // pass 1: 32-granular partial sums
    #pragma unroll
    for (int ss = 0; ss < 8; ++ss) {
        int sub = sg * 8 + ss;
        const float* p = iF + base + sub * 32;
        float s = 0.f;
        #pragma unroll
        for (int i = 0; i < 32; i += 4) {
            float4 v = *(const float4*)(p + i);
            s += v.x + v.y + v.z + v.w;
        }
        sums[r][sub] = s;
    }
    __syncthreads();
    if (tid < 32) {
        float run = 0.f;
        for (int s = 0; s < 64; ++s) {
            float t = sums[tid][s];
            sums[tid][s] = run;
            run += t;
        }
    }
    __syncthreads();

    for (int c = 0; c < 8; ++c) {
        int tl0 = sg * 32;
        float run = sums[r][c * 8 + sg];
        const float* pf = iF + base + c * 256 + tl0;
        const _Float16* pm = mag + base + c * 256 + tl0;
        for (int i = 0; i < 32; ++i) {
            run += pf[i];
            float m = (float)pm[i];
            float sn, cs;
            sincosf(run, &sn, &cs);
            ta[tl0 + i][r] = (_Float16)(m * cs);
            tb[tl0 + i][r] = (_Float16)(m * sn);
        }
        __syncthreads();
        size_t mrow = (size_t)b * T_ + c * 256 + tid;
        if (kt < 16) {
            _Float16* dstA = specT + mrow * KSPEC + kt * 32;
            _Float16* dstB = specT + mrow * KSPEC + 528 + kt * 32;
            *(h8*)(dstA + 0)  = *(const h8*)&ta[tid][0];
            *(h8*)(dstA + 8)  = *(const h8*)&ta[tid][8];
            *(h8*)(dstA + 16) = *(const h8*)&ta[tid][16];
            *(h8*)(dstA + 24) = *(const h8*)&ta[tid][24];
            *(h8*)(dstB + 0)  = *(const h8*)&tb[tid][0];
            *(h8*)(dstB + 8)  = *(const h8*)&tb[tid][8];
            *(h8*)(dstB + 16) = *(const h8*)&tb[tid][16];
            *(h8*)(dstB + 24) = *(const h8*)&tb[tid][24];
        } else {
            specT[mrow * KSPEC + 512] = ta[tid][0];
        }
        __syncthreads();
    }
}

// ---------------------------------------------------------------------------
// GEMM2 (iDFT): frames[m][j] = sum_r specT[m][r] * basisT[j][r], K=1056.
// Single f16 pass. Output f16.
// ---------------------------------------------------------------------------
__global__ __launch_bounds__(256) void k_gemm_idft(
    const _Float16* __restrict__ specT, const _Float16* __restrict__ basisT,
    _Float16* __restrict__ frames) {
    __shared__ _Float16 sA[128 * 32];
    __shared__ _Float16 sB[128 * 32];
    const int tid = threadIdx.x;
    const int lane = tid & 63;
    const int wv = tid >> 6;
    const int wr = wv >> 1, wc = wv & 1;
    const int quad = lane >> 4, l16 = lane & 15;
    const int j0 = blockIdx.x * 128;
    const int m0 = blockIdx.y * 128;

    const int cid0 = wv * 128 + lane;
    const int cid1 = cid0 + 64;
    const int ar0 = cid0 >> 2, aq0 = cid0 & 3;
    const int ar1 = cid1 >> 2, aq1 = cid1 & 3;

    f4 acc[4][4];
    f4 zero = {0.f, 0.f, 0.f, 0.f};
    #pragma unroll
    for (int i = 0; i < 4; ++i)
        #pragma unroll
        for (int j = 0; j < 4; ++j) acc[i][j] = zero;

    for (int k0 = 0; k0 < KSPEC; k0 += 32) {
        _Float16* dA = &sA[wv * 128 * 8];
        _Float16* dB = &sB[wv * 128 * 8];
        GLOAD_LDS16(specT + (size_t)(m0 + ar0) * KSPEC + k0 + aq0 * 8, dA);
        GLOAD_LDS16(specT + (size_t)(m0 + ar1) * KSPEC + k0 + aq1 * 8, dA + 512);
        GLOAD_LDS16(basisT + (size_t)(j0 + ar0) * KSPEC + k0 + aq0 * 8, dB);
        GLOAD_LDS16(basisT + (size_t)(j0 + ar1) * KSPEC + k0 + aq1 * 8, dB + 512);
        __syncthreads();

        h8 af[4], bf[4];
        #pragma unroll
        for (int rt = 0; rt < 4; ++rt) {
            int row = wr * 64 + rt * 16 + l16;
            af[rt] = *(const h8*)&sA[row * 32 + quad * 8];
        }
        #pragma unroll
        for (int ct = 0; ct < 4; ++ct) {
            int col = wc * 64 + ct * 16 + l16;
            bf[ct] = *(const h8*)&sB[col * 32 + quad * 8];
        }
        #pragma unroll
        for (int rt = 0; rt < 4; ++rt)
            #pragma unroll
            for (int ct = 0; ct < 4; ++ct)
                acc[rt][ct] = __builtin_amdgcn_mfma_f32_16x16x32_f16(af[rt], bf[ct], acc[rt][ct], 0, 0, 0);
        __syncthreads();
    }

    #pragma unroll
    for (int rt = 0; rt < 4; ++rt) {
        int mbase = m0 + wr * 64 + rt * 16 + quad * 4;
        #pragma unroll
        for (int ct = 0; ct < 4; ++ct) {
            int col = j0 + wc * 64 + ct * 16 + l16;
            f4 v = acc[rt][ct];
            #pragma unroll
            for (int r = 0; r < 4; ++r)
                frames[(size_t)(mbase + r) * NFFT + col] = (_Float16)v[r];
        }
    }
}

// ---------------------------------------------------------------------------
// OLA gather + envelope divide + clip (frames are f16, window pre-applied)
// ---------------------------------------------------------------------------
__global__ void k_ola(const _Float16* __restrict__ frames, float* __restrict__ out) {
    const int s_out = blockIdx.x * 256 + threadIdx.x;
    const int b = blockIdx.y;
    const int s = s_out + NFFT / 2;
    int t_lo = (s - (NFFT - HOP)) >> 8;
    if (t_lo < 0) t_lo = 0;
    int t_hi = s >> 8;
    if (t_hi > T_ - 1) t_hi = T_ - 1;
    float acc = 0.0f, env = 0.0f;
    for (int t = t_lo; t <= t_hi; ++t) {
        int j = s - (t << 8);
        acc += (float)frames[((size_t)(b * T_ + t) << 10) + j];
        float w = 0.5f * (1.0f - __cosf((float)j * (TWO_PI_F / NFFT)));
        env += w * w;
    }
    float r = acc / env;
    r = fminf(fmaxf(r, -1.0f), 1.0f);
    out[(size_t)b * OUT_LEN + s_out] = r;
}

// ---------------------------------------------------------------------------
extern "C" void kernel_launch(void* const* d_in, const int* in_sizes, int n_in,
                              void* d_out, int out_size, void* d_ws, size_t ws_size,
                              hipStream_t stream) {
    const float* x  = (const float*)d_in[0];
    const float* Wm = (const float*)d_in[1];
    const float* bm = (const float*)d_in[2];
    const float* Wp = (const float*)d_in[3];
    const float* bp = (const float*)d_in[4];
    float* out = (float*)d_out;

    char* ws = (char*)d_ws;
    // layout (bytes):
    const size_t OFF_MAG   = 0;                        // 640*32768*2   = 41,943,040
    const size_t OFF_PH    = 41943040;                 // 640*32768*4   = 83,886,080
    const size_t OFF_XH    = 125829120;                // 16*2048*1024*2= 67,108,864
    const size_t OFF_XL    = 192937984;                // 67,108,864
    const size_t OFF_WH    = 260046848;                // 1280*1024*2   =  2,621,440
    const size_t OFF_WL    = 262668288;                //  2,621,440
    const size_t OFF_BIAS  = 265289728;                //  5,120
    const size_t OFF_BASIS = 265294848;                // 1024*1056*2   =  2,162,688
    // total 267,457,536 B. Aliases (sequential stages):
    //   specT  (32768*1056*2 = 69,206,016) -> OFF_XH  (xT dead after gemm_head)
    //   frames (32768*1024*2 = 67,108,864) -> 0       (buf1 dead after scan)

    _Float16* bufmag = (_Float16*)(ws + OFF_MAG);
    float*    bufph  = (float*)(ws + OFF_PH);
    _Float16* xh     = (_Float16*)(ws + OFF_XH);
    _Float16* xl     = (_Float16*)(ws + OFF_XL);
    _Float16* Wh     = (_Float16*)(ws + OFF_WH);
    _Float16* Wl     = (_Float16*)(ws + OFF_WL);
    float*    biasp  = (float*)(ws + OFF_BIAS);
    _Float16* basisT = (_Float16*)(ws + OFF_BASIS);
    _Float16* specT  = (_Float16*)(ws + OFF_XH);
    _Float16* frames = (_Float16*)(ws + OFF_MAG);

    k_convert_x<<<dim3(DIM / 64, T_ / 64, B_), 256, 0, stream>>>(x, xh, xl);
    k_pack_w<<<dim3(NROWS * DIM / 256), 256, 0, stream>>>(Wm, Wp, Wh, Wl);
    k_pack_bias<<<dim3((NROWS + 255) / 256), 256, 0, stream>>>(bm, bp, biasp);
    k_basisT<<<dim3((NFFT * KSPEC + 255) / 256), 256, 0, stream>>>(basisT);

    k_gemm_head<<<dim3(NROWS / 128, M_TOT / 128), 256, 0, stream>>>(
        Wh, Wl, xh, xl, biasp, bufmag, bufph);
    k_scan<<<dim3(17, B_), 256, 0, stream>>>(bufmag, bufph, specT);
    k_gemm_idft<<<dim3(NFFT / 128, M_TOT / 128), 256, 0, stream>>>(specT, basisT, frames);
    k_ola<<<dim3(OUT_LEN / 256, B_), 256, 0, stream>>>(frames, out);
}

// Round 3
// 752.771 us; speedup vs baseline: 2.7048x; 1.0611x over previous
//
#include <hip/hip_runtime.h>
#include <math.h>

// Problem constants
constexpr int B_   = 16;
constexpr int DIM  = 1024;
constexpr int T_   = 2048;
constexpr int NFFT = 1024;
constexpr int HOP  = 256;
constexpr int NBINS = 513;
constexpr int M_TOT = B_ * T_;            // 32768
constexpr int OUT_LEN = HOP * (T_ - 1);   // 524032
constexpr int NPAD = 640;                 // padded rows per head region
constexpr int NROWS = 2 * NPAD;           // 1280 packed W rows
constexpr int KSPEC = 1056;               // spec/basis K (513 cos + 15 pad + 512 sin + 16 pad)
constexpr float TWO_PI_F = 6.28318530717958647692f;
constexpr float PI_F = 3.14159265358979323846f;

typedef _Float16 h8 __attribute__((ext_vector_type(8)));
typedef float f4 __attribute__((ext_vector_type(4)));

#define GLOAD_LDS16(g, l) __builtin_amdgcn_global_load_lds(                  \
    (const __attribute__((address_space(1))) void*)(g),                      \
    (__attribute__((address_space(3))) void*)(l), 16, 0, 0)

// ---------------------------------------------------------------------------
// Convert x [b][k][t] f32 -> xT hi/lo [b][t][k] f16 (64x64 tile transpose)
// ---------------------------------------------------------------------------
__global__ __launch_bounds__(256) void k_convert_x(
    const float* __restrict__ x, _Float16* __restrict__ xh, _Float16* __restrict__ xl) {
    __shared__ float tile[64][65];
    const int tid = threadIdx.x;
    const int k0 = blockIdx.x * 64;
    const int t0 = blockIdx.y * 64;
    const int b  = blockIdx.z;
    {
        int kr = tid >> 2;
        int tq = (tid & 3) * 16;
        const float* src = x + ((size_t)(b * DIM + k0 + kr)) * T_ + t0 + tq;
        #pragma unroll
        for (int i = 0; i < 4; ++i) {
            float4 v = *(const float4*)(src + i * 4);
            tile[kr][tq + i * 4 + 0] = v.x;
            tile[kr][tq + i * 4 + 1] = v.y;
            tile[kr][tq + i * 4 + 2] = v.z;
            tile[kr][tq + i * 4 + 3] = v.w;
        }
    }
    __syncthreads();
    {
        int tr = tid >> 2;
        int kq = (tid & 3) * 16;
        _Float16 hv[16], lv[16];
        #pragma unroll
        for (int i = 0; i < 16; ++i) {
            float w = tile[kq + i][tr];
            _Float16 h = (_Float16)w;
            hv[i] = h;
            lv[i] = (_Float16)(w - (float)h);
        }
        size_t base = ((size_t)(b * T_ + t0 + tr)) * DIM + k0 + kq;
        *(h8*)(xh + base)     = *(const h8*)&hv[0];
        *(h8*)(xh + base + 8) = *(const h8*)&hv[8];
        *(h8*)(xl + base)     = *(const h8*)&lv[0];
        *(h8*)(xl + base + 8) = *(const h8*)&lv[8];
    }
}

// ---------------------------------------------------------------------------
// Pack W: rows 0..512 = W_mag, 513..639 zero, 640..1152 = W_phase, rest zero
// ---------------------------------------------------------------------------
__global__ void k_pack_w(const float* __restrict__ Wm, const float* __restrict__ Wp,
                         _Float16* __restrict__ Wh, _Float16* __restrict__ Wl) {
    int idx = blockIdx.x * 256 + threadIdx.x;
    if (idx >= NROWS * DIM) return;
    int n = idx >> 10, k = idx & 1023;
    float w = 0.f;
    if (n < NBINS) w = Wm[(size_t)n * DIM + k];
    else if (n >= NPAD && n < NPAD + NBINS) w = Wp[(size_t)(n - NPAD) * DIM + k];
    _Float16 h = (_Float16)w;
    Wh[idx] = h;
    Wl[idx] = (_Float16)(w - (float)h);
}

__global__ void k_pack_bias(const float* __restrict__ bm, const float* __restrict__ bp,
                            float* __restrict__ biasp) {
    int n = blockIdx.x * 256 + threadIdx.x;
    if (n >= NROWS) return;
    float v = 0.f;
    if (n < NBINS) v = bm[n];
    else if (n >= NPAD && n < NPAD + NBINS) v = bp[n - NPAD];
    biasp[n] = v;
}

// ---------------------------------------------------------------------------
// basisT[j][r] f16, stride KSPEC. r<513: cos bin k=r (w=1 for k=0,512 else 2);
// 528<=r<1040: -sin bin k=r-528 (w=2; k=0 row is 0 anyway). Pads are ZERO.
// Includes 1/N and Hann window.
// ---------------------------------------------------------------------------
__global__ void k_basisT(_Float16* __restrict__ basisT) {
    int idx = blockIdx.x * 256 + threadIdx.x;
    if (idx >= NFFT * KSPEC) return;
    int j = idx / KSPEC;
    int r = idx - j * KSPEC;
    float win = 0.5f * (1.0f - __cosf((float)j * (TWO_PI_F / NFFT)));
    float val = 0.f;
    if (r < NBINS) {
        int k = r;
        int m = (k * j) & (NFFT - 1);
        float s, c;
        __sincosf((float)m * (TWO_PI_F / NFFT), &s, &c);
        float w = (k == 0 || k == NFFT / 2) ? 1.0f : 2.0f;
        val = w * (1.0f / NFFT) * c * win;
    } else if (r >= 528 && r < 1040) {
        int k = r - 528;
        int m = (k * j) & (NFFT - 1);
        float s, c;
        __sincosf((float)m * (TWO_PI_F / NFFT), &s, &c);
        val = -2.0f * (1.0f / NFFT) * s * win;
    }
    basisT[idx] = (_Float16)val;
}

// ---------------------------------------------------------------------------
// GEMM1 (heads): D[n][m] = sum_k Wpack[n][k] * x[b][k][t].
// 128x128 tile, BK=32, 4 waves. XCD-swizzled 1-D grid: all 10 n-tiles of a
// given m-tile land on the SAME XCD (L%8) so the shared x slice stays in
// that XCD's private L2 (R2 showed 4.2x HBM over-fetch from cross-XCD
// replication of the x re-reads).
// Mag blocks (n0<640): 1-pass hi*hi, epilogue exp(clip(.)) -> f16.
// Phase blocks: 3-pass (hi*hi + hi*lo + lo*hi), epilogue clip -> f32.
// ---------------------------------------------------------------------------
__global__ __launch_bounds__(256) void k_gemm_head(
    const _Float16* __restrict__ Wh, const _Float16* __restrict__ Wl,
    const _Float16* __restrict__ xh, const _Float16* __restrict__ xl,
    const float* __restrict__ biasp,
    _Float16* __restrict__ bufmag, float* __restrict__ bufph) {
    __shared__ _Float16 sA[2][128 * 32];
    __shared__ _Float16 sB[2][128 * 32];
    const int tid = threadIdx.x;
    const int lane = tid & 63;
    const int wv = tid >> 6;
    const int wr = wv >> 1, wc = wv & 1;
    const int quad = lane >> 4, l16 = lane & 15;
    // XCD swizzle: L in [0,2560); xcd = L%8; idx = L/8 in [0,320)
    const int L = blockIdx.x;
    const int xcd = L & 7;
    const int idx = L >> 3;
    const int n_tile = idx % 10;
    const int m_tile = (idx / 10) * 8 + xcd;   // [0,256)
    const int n0 = n_tile * 128;
    const int m0 = m_tile * 128;
    const bool ph = (n0 >= NPAD);
    const int b = m0 >> 11;
    const int t0 = m0 & (T_ - 1);
    const size_t xbase = ((size_t)(b * T_ + t0)) * DIM;

    const int cid0 = wv * 128 + lane;
    const int cid1 = cid0 + 64;
    const int ar0 = cid0 >> 2, aq0 = cid0 & 3;
    const int ar1 = cid1 >> 2, aq1 = cid1 & 3;

    f4 acc[4][4];
    f4 zero = {0.f, 0.f, 0.f, 0.f};
    #pragma unroll
    for (int i = 0; i < 4; ++i)
        #pragma unroll
        for (int j = 0; j < 4; ++j) acc[i][j] = zero;

    for (int k0 = 0; k0 < DIM; k0 += 32) {
        _Float16* dA = &sA[0][wv * 128 * 8];
        _Float16* dB = &sB[0][wv * 128 * 8];
        GLOAD_LDS16(Wh + ((size_t)(n0 + ar0) << 10) + k0 + aq0 * 8, dA);
        GLOAD_LDS16(Wh + ((size_t)(n0 + ar1) << 10) + k0 + aq1 * 8, dA + 512);
        GLOAD_LDS16(xh + xbase + ((size_t)ar0 << 10) + k0 + aq0 * 8, dB);
        GLOAD_LDS16(xh + xbase + ((size_t)ar1 << 10) + k0 + aq1 * 8, dB + 512);
        if (ph) {
            _Float16* dAl = &sA[1][wv * 128 * 8];
            _Float16* dBl = &sB[1][wv * 128 * 8];
            GLOAD_LDS16(Wl + ((size_t)(n0 + ar0) << 10) + k0 + aq0 * 8, dAl);
            GLOAD_LDS16(Wl + ((size_t)(n0 + ar1) << 10) + k0 + aq1 * 8, dAl + 512);
            GLOAD_LDS16(xl + xbase + ((size_t)ar0 << 10) + k0 + aq0 * 8, dBl);
            GLOAD_LDS16(xl + xbase + ((size_t)ar1 << 10) + k0 + aq1 * 8, dBl + 512);
        }
        __syncthreads();

        h8 aH[4], bH[4], aL[4], bL[4];
        #pragma unroll
        for (int rt = 0; rt < 4; ++rt) {
            int row = wr * 64 + rt * 16 + l16;
            aH[rt] = *(const h8*)&sA[0][row * 32 + quad * 8];
        }
        #pragma unroll
        for (int ct = 0; ct < 4; ++ct) {
            int col = wc * 64 + ct * 16 + l16;
            bH[ct] = *(const h8*)&sB[0][col * 32 + quad * 8];
        }
        if (ph) {
            #pragma unroll
            for (int rt = 0; rt < 4; ++rt) {
                int row = wr * 64 + rt * 16 + l16;
                aL[rt] = *(const h8*)&sA[1][row * 32 + quad * 8];
            }
            #pragma unroll
            for (int ct = 0; ct < 4; ++ct) {
                int col = wc * 64 + ct * 16 + l16;
                bL[ct] = *(const h8*)&sB[1][col * 32 + quad * 8];
            }
        }
        #pragma unroll
        for (int rt = 0; rt < 4; ++rt)
            #pragma unroll
            for (int ct = 0; ct < 4; ++ct) {
                acc[rt][ct] = __builtin_amdgcn_mfma_f32_16x16x32_f16(aH[rt], bH[ct], acc[rt][ct], 0, 0, 0);
                if (ph) {
                    acc[rt][ct] = __builtin_amdgcn_mfma_f32_16x16x32_f16(aH[rt], bL[ct], acc[rt][ct], 0, 0, 0);
                    acc[rt][ct] = __builtin_amdgcn_mfma_f32_16x16x32_f16(aL[rt], bH[ct], acc[rt][ct], 0, 0, 0);
                }
            }
        __syncthreads();
    }

    #pragma unroll
    for (int rt = 0; rt < 4; ++rt) {
        int nbase = n0 + wr * 64 + rt * 16 + quad * 4;
        #pragma unroll
        for (int ct = 0; ct < 4; ++ct) {
            int col = m0 + wc * 64 + ct * 16 + l16;
            f4 v = acc[rt][ct];
            #pragma unroll
            for (int r = 0; r < 4; ++r) {
                int n = nbase + r;
                float val = v[r] + biasp[n];
                if (!ph) {
                    val = fminf(fmaxf(val, -10.f), 10.f);
                    bufmag[(size_t)n * M_TOT + col] = (_Float16)expf(val);
                } else {
                    val = fminf(fmaxf(val, -PI_F), PI_F);
                    bufph[(size_t)(n - NPAD) * M_TOT + col] = val;
                }
            }
        }
    }
}

// ---------------------------------------------------------------------------
// Scan: per (k-tile of 32, b): cumsum inst_freq over t, spec = mag*e^{i phase},
// written TRANSPOSED to specT[m][KSPEC] f16: cos part -> col k, sin part ->
// col 528+k. kt==16 (k=512): only col 512 written.
// ---------------------------------------------------------------------------
__global__ __launch_bounds__(256) void k_scan(
    const _Float16* __restrict__ mag, const float* __restrict__ iF,
    _Float16* __restrict__ specT) {
    __shared__ float sums[32][65];
    __shared__ _Float16 ta[256][32];
    __shared__ _Float16 tb[256][32];
    const int tid = threadIdx.x;
    const int r = tid & 31;
    const int sg = tid >> 5;        // 0..7
    const int kt = blockIdx.x;      // 0..16
    const int b = blockIdx.y;
    const int k = kt * 32 + r;      // rows up to 543 exist (pad rows are clean zeros)
    const size_t base = (size_t)k * M_TOT + b * T_;

    // pass 1: 32-granular partial sums
    #pragma unroll
    for (int ss = 0; ss < 8; ++ss) {
        int sub = sg * 8 + ss;
        const float* p = iF + base + sub * 32;
        float s = 0.f;
        #pragma unroll
        for (int i = 0; i < 32; i += 4) {
            float4 v = *(const float4*)(p + i);
            s += v.x + v.y + v.z + v.w;
        }
        sums[r][sub] = s;
    }
    __syncthreads();
    if (tid < 32) {
        float run = 0.f;
        for (int s = 0; s < 64; ++s) {
            float t = sums[tid][s];
            sums[tid][s] = run;
            run += t;
        }
    }
    __syncthreads();

    for (int c = 0; c < 8; ++c) {
        int tl0 = sg * 32;
        float run = sums[r][c * 8 + sg];
        const float* pf = iF + base + c * 256 + tl0;
        const _Float16* pm = mag + base + c * 256 + tl0;
        for (int i = 0; i < 32; ++i) {
            run += pf[i];
            float m = (float)pm[i];
            float sn, cs;
            sincosf(run, &sn, &cs);
            ta[tl0 + i][r] = (_Float16)(m * cs);
            tb[tl0 + i][r] = (_Float16)(m * sn);
        }
        __syncthreads();
        size_t mrow = (size_t)b * T_ + c * 256 + tid;
        if (kt < 16) {
            _Float16* dstA = specT + mrow * KSPEC + kt * 32;
            _Float16* dstB = specT + mrow * KSPEC + 528 + kt * 32;
            *(h8*)(dstA + 0)  = *(const h8*)&ta[tid][0];
            *(h8*)(dstA + 8)  = *(const h8*)&ta[tid][8];
            *(h8*)(dstA + 16) = *(const h8*)&ta[tid][16];
            *(h8*)(dstA + 24) = *(const h8*)&ta[tid][24];
            *(h8*)(dstB + 0)  = *(const h8*)&tb[tid][0];
            *(h8*)(dstB + 8)  = *(const h8*)&tb[tid][8];
            *(h8*)(dstB + 16) = *(const h8*)&tb[tid][16];
            *(h8*)(dstB + 24) = *(const h8*)&tb[tid][24];
        } else {
            specT[mrow * KSPEC + 512] = ta[tid][0];
        }
        __syncthreads();
    }
}

// ---------------------------------------------------------------------------
// GEMM2 (iDFT): frames[m][j] = sum_r specT[m][r] * basisT[j][r], K=1056.
// Single f16 pass. Output f16. XCD-swizzled 1-D grid (same rationale as
// k_gemm_head: 8 j-tiles re-read each specT m-slice).
// ---------------------------------------------------------------------------
__global__ __launch_bounds__(256) void k_gemm_idft(
    const _Float16* __restrict__ specT, const _Float16* __restrict__ basisT,
    _Float16* __restrict__ frames) {
    __shared__ _Float16 sA[128 * 32];
    __shared__ _Float16 sB[128 * 32];
    const int tid = threadIdx.x;
    const int lane = tid & 63;
    const int wv = tid >> 6;
    const int wr = wv >> 1, wc = wv & 1;
    const int quad = lane >> 4, l16 = lane & 15;
    // XCD swizzle: L in [0,2048); xcd = L%8; idx = L/8 in [0,256)
    const int L = blockIdx.x;
    const int xcd = L & 7;
    const int idx = L >> 3;
    const int j_tile = idx & 7;
    const int m_tile = (idx >> 3) * 8 + xcd;   // [0,256)
    const int j0 = j_tile * 128;
    const int m0 = m_tile * 128;

    const int cid0 = wv * 128 + lane;
    const int cid1 = cid0 + 64;
    const int ar0 = cid0 >> 2, aq0 = cid0 & 3;
    const int ar1 = cid1 >> 2, aq1 = cid1 & 3;

    f4 acc[4][4];
    f4 zero = {0.f, 0.f, 0.f, 0.f};
    #pragma unroll
    for (int i = 0; i < 4; ++i)
        #pragma unroll
        for (int j = 0; j < 4; ++j) acc[i][j] = zero;

    for (int k0 = 0; k0 < KSPEC; k0 += 32) {
        _Float16* dA = &sA[wv * 128 * 8];
        _Float16* dB = &sB[wv * 128 * 8];
        GLOAD_LDS16(specT + (size_t)(m0 + ar0) * KSPEC + k0 + aq0 * 8, dA);
        GLOAD_LDS16(specT + (size_t)(m0 + ar1) * KSPEC + k0 + aq1 * 8, dA + 512);
        GLOAD_LDS16(basisT + (size_t)(j0 + ar0) * KSPEC + k0 + aq0 * 8, dB);
        GLOAD_LDS16(basisT + (size_t)(j0 + ar1) * KSPEC + k0 + aq1 * 8, dB + 512);
        __syncthreads();

        h8 af[4], bf[4];
        #pragma unroll
        for (int rt = 0; rt < 4; ++rt) {
            int row = wr * 64 + rt * 16 + l16;
            af[rt] = *(const h8*)&sA[row * 32 + quad * 8];
        }
        #pragma unroll
        for (int ct = 0; ct < 4; ++ct) {
            int col = wc * 64 + ct * 16 + l16;
            bf[ct] = *(const h8*)&sB[col * 32 + quad * 8];
        }
        #pragma unroll
        for (int rt = 0; rt < 4; ++rt)
            #pragma unroll
            for (int ct = 0; ct < 4; ++ct)
                acc[rt][ct] = __builtin_amdgcn_mfma_f32_16x16x32_f16(af[rt], bf[ct], acc[rt][ct], 0, 0, 0);
        __syncthreads();
    }

    #pragma unroll
    for (int rt = 0; rt < 4; ++rt) {
        int mbase = m0 + wr * 64 + rt * 16 + quad * 4;
        #pragma unroll
        for (int ct = 0; ct < 4; ++ct) {
            int col = j0 + wc * 64 + ct * 16 + l16;
            f4 v = acc[rt][ct];
            #pragma unroll
            for (int r = 0; r < 4; ++r)
                frames[(size_t)(mbase + r) * NFFT + col] = (_Float16)v[r];
        }
    }
}

// ---------------------------------------------------------------------------
// OLA gather + envelope divide + clip (frames are f16, window pre-applied)
// ---------------------------------------------------------------------------
__global__ void k_ola(const _Float16* __restrict__ frames, float* __restrict__ out) {
    const int s_out = blockIdx.x * 256 + threadIdx.x;
    const int b = blockIdx.y;
    const int s = s_out + NFFT / 2;
    int t_lo = (s - (NFFT - HOP)) >> 8;
    if (t_lo < 0) t_lo = 0;
    int t_hi = s >> 8;
    if (t_hi > T_ - 1) t_hi = T_ - 1;
    float acc = 0.0f, env = 0.0f;
    for (int t = t_lo; t <= t_hi; ++t) {
        int j = s - (t << 8);
        acc += (float)frames[((size_t)(b * T_ + t) << 10) + j];
        float w = 0.5f * (1.0f - __cosf((float)j * (TWO_PI_F / NFFT)));
        env += w * w;
    }
    float r = acc / env;
    r = fminf(fmaxf(r, -1.0f), 1.0f);
    out[(size_t)b * OUT_LEN + s_out] = r;
}

// ---------------------------------------------------------------------------
extern "C" void kernel_launch(void* const* d_in, const int* in_sizes, int n_in,
                              void* d_out, int out_size, void* d_ws, size_t ws_size,
                              hipStream_t stream) {
    const float* x  = (const float*)d_in[0];
    const float* Wm = (const float*)d_in[1];
    const float* bm = (const float*)d_in[2];
    const float* Wp = (const float*)d_in[3];
    const float* bp = (const float*)d_in[4];
    float* out = (float*)d_out;

    char* ws = (char*)d_ws;
    const size_t OFF_MAG   = 0;                        // 640*32768*2   = 41,943,040
    const size_t OFF_PH    = 41943040;                 // 640*32768*4   = 83,886,080
    const size_t OFF_XH    = 125829120;                // 16*2048*1024*2= 67,108,864
    const size_t OFF_XL    = 192937984;                // 67,108,864
    const size_t OFF_WH    = 260046848;                // 1280*1024*2   =  2,621,440
    const size_t OFF_WL    = 262668288;                //  2,621,440
    const size_t OFF_BIAS  = 265289728;                //  5,120
    const size_t OFF_BASIS = 265294848;                // 1024*1056*2   =  2,162,688
    // total 267,457,536 B. Aliases: specT -> OFF_XH, frames -> 0

    _Float16* bufmag = (_Float16*)(ws + OFF_MAG);
    float*    bufph  = (float*)(ws + OFF_PH);
    _Float16* xh     = (_Float16*)(ws + OFF_XH);
    _Float16* xl     = (_Float16*)(ws + OFF_XL);
    _Float16* Wh     = (_Float16*)(ws + OFF_WH);
    _Float16* Wl     = (_Float16*)(ws + OFF_WL);
    float*    biasp  = (float*)(ws + OFF_BIAS);
    _Float16* basisT = (_Float16*)(ws + OFF_BASIS);
    _Float16* specT  = (_Float16*)(ws + OFF_XH);
    _Float16* frames = (_Float16*)(ws + OFF_MAG);

    k_convert_x<<<dim3(DIM / 64, T_ / 64, B_), 256, 0, stream>>>(x, xh, xl);
    k_pack_w<<<dim3(NROWS * DIM / 256), 256, 0, stream>>>(Wm, Wp, Wh, Wl);
    k_pack_bias<<<dim3((NROWS + 255) / 256), 256, 0, stream>>>(bm, bp, biasp);
    k_basisT<<<dim3((NFFT * KSPEC + 255) / 256), 256, 0, stream>>>(basisT);

    k_gemm_head<<<dim3((NROWS / 128) * (M_TOT / 128)), 256, 0, stream>>>(
        Wh, Wl, xh, xl, biasp, bufmag, bufph);
    k_scan<<<dim3(17, B_), 256, 0, stream>>>(bufmag, bufph, specT);
    k_gemm_idft<<<dim3((NFFT / 128) * (M_TOT / 128)), 256, 0, stream>>>(specT, basisT, frames);
    k_ola<<<dim3(OUT_LEN / 256, B_), 256, 0, stream>>>(frames, out);
}

// Round 4
// 627.865 us; speedup vs baseline: 3.2429x; 1.1989x over previous
//
#include <hip/hip_runtime.h>
#include <math.h>

// Problem constants
constexpr int B_   = 16;
constexpr int DIM  = 1024;
constexpr int T_   = 2048;
constexpr int NFFT = 1024;
constexpr int HOP  = 256;
constexpr int NBINS = 513;
constexpr int M_TOT = B_ * T_;            // 32768
constexpr int OUT_LEN = HOP * (T_ - 1);   // 524032
constexpr int NPAD = 640;                 // padded rows per head region
constexpr int NROWS = 2 * NPAD;           // 1280 packed W rows
constexpr int KSPEC = 1056;               // spec/basis K (513 cos + pad + 512 sin + pad)
constexpr float TWO_PI_F = 6.28318530717958647692f;
constexpr float PI_F = 3.14159265358979323846f;

typedef _Float16 h8 __attribute__((ext_vector_type(8)));
typedef float fv16 __attribute__((ext_vector_type(16)));

#define GLOAD_LDS16(g, l) __builtin_amdgcn_global_load_lds(                  \
    (const __attribute__((address_space(1))) void*)(g),                      \
    (__attribute__((address_space(3))) void*)(l), 16, 0, 0)

// XOR swizzle of 16B groups within a 64B LDS row: kills the 8-way bank
// aliasing of row-stride-64B fragment reads (R3: 1.57e7 conflict cycles).
__device__ __forceinline__ int xorf(int row) { return (row & 3) ^ ((row >> 2) & 3); }

// ---------------------------------------------------------------------------
// Convert x [b][k][t] f32 -> xT hi/lo [b][t][k] f16 (64x64 tile transpose)
// ---------------------------------------------------------------------------
__global__ __launch_bounds__(256) void k_convert_x(
    const float* __restrict__ x, _Float16* __restrict__ xh, _Float16* __restrict__ xl) {
    __shared__ float tile[64][65];
    const int tid = threadIdx.x;
    const int k0 = blockIdx.x * 64;
    const int t0 = blockIdx.y * 64;
    const int b  = blockIdx.z;
    {
        int kr = tid >> 2;
        int tq = (tid & 3) * 16;
        const float* src = x + ((size_t)(b * DIM + k0 + kr)) * T_ + t0 + tq;
        #pragma unroll
        for (int i = 0; i < 4; ++i) {
            float4 v = *(const float4*)(src + i * 4);
            tile[kr][tq + i * 4 + 0] = v.x;
            tile[kr][tq + i * 4 + 1] = v.y;
            tile[kr][tq + i * 4 + 2] = v.z;
            tile[kr][tq + i * 4 + 3] = v.w;
        }
    }
    __syncthreads();
    {
        int tr = tid >> 2;
        int kq = (tid & 3) * 16;
        _Float16 hv[16], lv[16];
        #pragma unroll
        for (int i = 0; i < 16; ++i) {
            float w = tile[kq + i][tr];
            _Float16 h = (_Float16)w;
            hv[i] = h;
            lv[i] = (_Float16)(w - (float)h);
        }
        size_t base = ((size_t)(b * T_ + t0 + tr)) * DIM + k0 + kq;
        *(h8*)(xh + base)     = *(const h8*)&hv[0];
        *(h8*)(xh + base + 8) = *(const h8*)&hv[8];
        *(h8*)(xl + base)     = *(const h8*)&lv[0];
        *(h8*)(xl + base + 8) = *(const h8*)&lv[8];
    }
}

// ---------------------------------------------------------------------------
// Pack W: rows 0..512 = W_mag, 513..639 zero, 640..1152 = W_phase, rest zero
// ---------------------------------------------------------------------------
__global__ void k_pack_w(const float* __restrict__ Wm, const float* __restrict__ Wp,
                         _Float16* __restrict__ Wh, _Float16* __restrict__ Wl) {
    int idx = blockIdx.x * 256 + threadIdx.x;
    if (idx >= NROWS * DIM) return;
    int n = idx >> 10, k = idx & 1023;
    float w = 0.f;
    if (n < NBINS) w = Wm[(size_t)n * DIM + k];
    else if (n >= NPAD && n < NPAD + NBINS) w = Wp[(size_t)(n - NPAD) * DIM + k];
    _Float16 h = (_Float16)w;
    Wh[idx] = h;
    Wl[idx] = (_Float16)(w - (float)h);
}

__global__ void k_pack_bias(const float* __restrict__ bm, const float* __restrict__ bp,
                            float* __restrict__ biasp) {
    int n = blockIdx.x * 256 + threadIdx.x;
    if (n >= NROWS) return;
    float v = 0.f;
    if (n < NBINS) v = bm[n];
    else if (n >= NPAD && n < NPAD + NBINS) v = bp[n - NPAD];
    biasp[n] = v;
}

// ---------------------------------------------------------------------------
// basisT[j][r] f16, stride KSPEC. Includes 1/N, irfft weights, Hann window.
// ---------------------------------------------------------------------------
__global__ void k_basisT(_Float16* __restrict__ basisT) {
    int idx = blockIdx.x * 256 + threadIdx.x;
    if (idx >= NFFT * KSPEC) return;
    int j = idx / KSPEC;
    int r = idx - j * KSPEC;
    float win = 0.5f * (1.0f - __cosf((float)j * (TWO_PI_F / NFFT)));
    float val = 0.f;
    if (r < NBINS) {
        int k = r;
        int m = (k * j) & (NFFT - 1);
        float s, c;
        __sincosf((float)m * (TWO_PI_F / NFFT), &s, &c);
        float w = (k == 0 || k == NFFT / 2) ? 1.0f : 2.0f;
        val = w * (1.0f / NFFT) * c * win;
    } else if (r >= 528 && r < 1040) {
        int k = r - 528;
        int m = (k * j) & (NFFT - 1);
        float s, c;
        __sincosf((float)m * (TWO_PI_F / NFFT), &s, &c);
        val = -2.0f * (1.0f / NFFT) * s * win;
    }
    basisT[idx] = (_Float16)val;
}

// ---------------------------------------------------------------------------
// GEMM mag: D[n][m] = exp(clip(Wmag.x + b)), rows 0..639, 1-pass f16.
// 128x128 tile, BK=32, 4 waves, 32x32x16 MFMA, XCD-swizzled grid,
// XOR-swizzled LDS.
// ---------------------------------------------------------------------------
__global__ __launch_bounds__(256) void k_gemm_mag(
    const _Float16* __restrict__ Wh, const _Float16* __restrict__ xh,
    const float* __restrict__ biasp, _Float16* __restrict__ bufmag) {
    __shared__ _Float16 sA[128 * 32];
    __shared__ _Float16 sB[128 * 32];
    const int tid = threadIdx.x;
    const int lane = tid & 63;
    const int wv = tid >> 6;
    const int wr = wv >> 1, wc = wv & 1;
    const int h = lane >> 5, r5 = lane & 31;
    const int L = blockIdx.x;
    const int xcd = L & 7;
    const int idx = L >> 3;
    const int n_tile = idx % 5;
    const int m_tile = (idx / 5) * 8 + xcd;
    const int n0 = n_tile * 128;
    const int m0 = m_tile * 128;
    const int b = m0 >> 11;
    const int t0 = m0 & (T_ - 1);
    const size_t xbase = ((size_t)(b * T_ + t0)) * DIM;

    const int cid0 = wv * 128 + lane, cid1 = cid0 + 64;
    const int ar0 = cid0 >> 2, g0 = (cid0 & 3) ^ xorf(ar0);
    const int ar1 = cid1 >> 2, g1 = (cid1 & 3) ^ xorf(ar1);
    const _Float16* gA0 = Wh + ((size_t)(n0 + ar0) << 10) + g0 * 8;
    const _Float16* gA1 = Wh + ((size_t)(n0 + ar1) << 10) + g1 * 8;
    const _Float16* gB0 = xh + xbase + ((size_t)ar0 << 10) + g0 * 8;
    const _Float16* gB1 = xh + xbase + ((size_t)ar1 << 10) + g1 * 8;
    _Float16* dA = &sA[wv * 1024];
    _Float16* dB = &sB[wv * 1024];

    const int xv = xorf(r5);
    int offA[2][2], offB[2][2];
    #pragma unroll
    for (int mt = 0; mt < 2; ++mt)
        #pragma unroll
        for (int s = 0; s < 2; ++s) {
            offA[mt][s] = (wr * 64 + mt * 32 + r5) * 32 + (((s << 1) | h) ^ xv) * 8;
            offB[mt][s] = (wc * 64 + mt * 32 + r5) * 32 + (((s << 1) | h) ^ xv) * 8;
        }

    fv16 acc[2][2];
    fv16 zero = {0,0,0,0,0,0,0,0,0,0,0,0,0,0,0,0};
    #pragma unroll
    for (int i = 0; i < 2; ++i)
        #pragma unroll
        for (int j = 0; j < 2; ++j) acc[i][j] = zero;

    for (int k0 = 0; k0 < DIM; k0 += 32) {
        GLOAD_LDS16(gA0 + k0, dA);
        GLOAD_LDS16(gA1 + k0, dA + 512);
        GLOAD_LDS16(gB0 + k0, dB);
        GLOAD_LDS16(gB1 + k0, dB + 512);
        __syncthreads();
        h8 af[2][2], bf[2][2];
        #pragma unroll
        for (int mt = 0; mt < 2; ++mt)
            #pragma unroll
            for (int s = 0; s < 2; ++s) {
                af[mt][s] = *(const h8*)&sA[offA[mt][s]];
                bf[mt][s] = *(const h8*)&sB[offB[mt][s]];
            }
        #pragma unroll
        for (int mt = 0; mt < 2; ++mt)
            #pragma unroll
            for (int nt = 0; nt < 2; ++nt)
                #pragma unroll
                for (int s = 0; s < 2; ++s)
                    acc[mt][nt] = __builtin_amdgcn_mfma_f32_32x32x16_f16(
                        af[mt][s], bf[nt][s], acc[mt][nt], 0, 0, 0);
        __syncthreads();
    }

    #pragma unroll
    for (int mt = 0; mt < 2; ++mt)
        #pragma unroll
        for (int nt = 0; nt < 2; ++nt) {
            int col = m0 + wc * 64 + nt * 32 + r5;
            #pragma unroll
            for (int reg = 0; reg < 16; ++reg) {
                int rl = (reg & 3) + 8 * (reg >> 2) + 4 * h;
                int n = n0 + wr * 64 + mt * 32 + rl;
                float val = acc[mt][nt][reg] + biasp[n];
                val = fminf(fmaxf(val, -10.f), 10.f);
                bufmag[(size_t)n * M_TOT + col] = (_Float16)expf(val);
            }
        }
}

// ---------------------------------------------------------------------------
// GEMM phase: rows 640..1279, 3-pass f16 split (hi*hi + hi*lo + lo*hi),
// epilogue clip -> f32. Same tiling as k_gemm_mag.
// ---------------------------------------------------------------------------
__global__ __launch_bounds__(256) void k_gemm_phase(
    const _Float16* __restrict__ Wh, const _Float16* __restrict__ Wl,
    const _Float16* __restrict__ xh, const _Float16* __restrict__ xl,
    const float* __restrict__ biasp, float* __restrict__ bufph) {
    __shared__ _Float16 sA[128 * 32];
    __shared__ _Float16 sB[128 * 32];
    __shared__ _Float16 sAl[128 * 32];
    __shared__ _Float16 sBl[128 * 32];
    const int tid = threadIdx.x;
    const int lane = tid & 63;
    const int wv = tid >> 6;
    const int wr = wv >> 1, wc = wv & 1;
    const int h = lane >> 5, r5 = lane & 31;
    const int L = blockIdx.x;
    const int xcd = L & 7;
    const int idx = L >> 3;
    const int n_tile = idx % 5;
    const int m_tile = (idx / 5) * 8 + xcd;
    const int n0 = NPAD + n_tile * 128;
    const int m0 = m_tile * 128;
    const int b = m0 >> 11;
    const int t0 = m0 & (T_ - 1);
    const size_t xbase = ((size_t)(b * T_ + t0)) * DIM;

    const int cid0 = wv * 128 + lane, cid1 = cid0 + 64;
    const int ar0 = cid0 >> 2, g0 = (cid0 & 3) ^ xorf(ar0);
    const int ar1 = cid1 >> 2, g1 = (cid1 & 3) ^ xorf(ar1);
    const size_t a0 = ((size_t)(n0 + ar0) << 10) + g0 * 8;
    const size_t a1 = ((size_t)(n0 + ar1) << 10) + g1 * 8;
    const size_t b0 = xbase + ((size_t)ar0 << 10) + g0 * 8;
    const size_t b1 = xbase + ((size_t)ar1 << 10) + g1 * 8;
    _Float16* dA = &sA[wv * 1024];
    _Float16* dB = &sB[wv * 1024];
    _Float16* dAl = &sAl[wv * 1024];
    _Float16* dBl = &sBl[wv * 1024];

    const int xv = xorf(r5);
    int offA[2][2], offB[2][2];
    #pragma unroll
    for (int mt = 0; mt < 2; ++mt)
        #pragma unroll
        for (int s = 0; s < 2; ++s) {
            offA[mt][s] = (wr * 64 + mt * 32 + r5) * 32 + (((s << 1) | h) ^ xv) * 8;
            offB[mt][s] = (wc * 64 + mt * 32 + r5) * 32 + (((s << 1) | h) ^ xv) * 8;
        }

    fv16 acc[2][2];
    fv16 zero = {0,0,0,0,0,0,0,0,0,0,0,0,0,0,0,0};
    #pragma unroll
    for (int i = 0; i < 2; ++i)
        #pragma unroll
        for (int j = 0; j < 2; ++j) acc[i][j] = zero;

    for (int k0 = 0; k0 < DIM; k0 += 32) {
        GLOAD_LDS16(Wh + a0 + k0, dA);
        GLOAD_LDS16(Wh + a1 + k0, dA + 512);
        GLOAD_LDS16(xh + b0 + k0, dB);
        GLOAD_LDS16(xh + b1 + k0, dB + 512);
        GLOAD_LDS16(Wl + a0 + k0, dAl);
        GLOAD_LDS16(Wl + a1 + k0, dAl + 512);
        GLOAD_LDS16(xl + b0 + k0, dBl);
        GLOAD_LDS16(xl + b1 + k0, dBl + 512);
        __syncthreads();
        h8 aH[2][2], bH[2][2], aL[2][2], bL[2][2];
        #pragma unroll
        for (int mt = 0; mt < 2; ++mt)
            #pragma unroll
            for (int s = 0; s < 2; ++s) {
                aH[mt][s] = *(const h8*)&sA[offA[mt][s]];
                bH[mt][s] = *(const h8*)&sB[offB[mt][s]];
                aL[mt][s] = *(const h8*)&sAl[offA[mt][s]];
                bL[mt][s] = *(const h8*)&sBl[offB[mt][s]];
            }
        #pragma unroll
        for (int mt = 0; mt < 2; ++mt)
            #pragma unroll
            for (int nt = 0; nt < 2; ++nt)
                #pragma unroll
                for (int s = 0; s < 2; ++s) {
                    acc[mt][nt] = __builtin_amdgcn_mfma_f32_32x32x16_f16(
                        aH[mt][s], bH[nt][s], acc[mt][nt], 0, 0, 0);
                    acc[mt][nt] = __builtin_amdgcn_mfma_f32_32x32x16_f16(
                        aH[mt][s], bL[nt][s], acc[mt][nt], 0, 0, 0);
                    acc[mt][nt] = __builtin_amdgcn_mfma_f32_32x32x16_f16(
                        aL[mt][s], bH[nt][s], acc[mt][nt], 0, 0, 0);
                }
        __syncthreads();
    }

    #pragma unroll
    for (int mt = 0; mt < 2; ++mt)
        #pragma unroll
        for (int nt = 0; nt < 2; ++nt) {
            int col = m0 + wc * 64 + nt * 32 + r5;
            #pragma unroll
            for (int reg = 0; reg < 16; ++reg) {
                int rl = (reg & 3) + 8 * (reg >> 2) + 4 * h;
                int n = n0 + wr * 64 + mt * 32 + rl;
                float val = acc[mt][nt][reg] + biasp[n];
                val = fminf(fmaxf(val, -PI_F), PI_F);
                bufph[(size_t)(n - NPAD) * M_TOT + col] = val;
            }
        }
}

// ---------------------------------------------------------------------------
// Scan: per (k-tile of 32, b): cumsum inst_freq over t, spec = mag*e^{i phase},
// written TRANSPOSED to specT[m][KSPEC] f16.
// ---------------------------------------------------------------------------
__global__ __launch_bounds__(256) void k_scan(
    const _Float16* __restrict__ mag, const float* __restrict__ iF,
    _Float16* __restrict__ specT) {
    __shared__ float sums[32][65];
    __shared__ _Float16 ta[256][32];
    __shared__ _Float16 tb[256][32];
    const int tid = threadIdx.x;
    const int r = tid & 31;
    const int sg = tid >> 5;
    const int kt = blockIdx.x;      // 0..16
    const int b = blockIdx.y;
    const int k = kt * 32 + r;
    const size_t base = (size_t)k * M_TOT + b * T_;

    #pragma unroll
    for (int ss = 0; ss < 8; ++ss) {
        int sub = sg * 8 + ss;
        const float* p = iF + base + sub * 32;
        float s = 0.f;
        #pragma unroll
        for (int i = 0; i < 32; i += 4) {
            float4 v = *(const float4*)(p + i);
            s += v.x + v.y + v.z + v.w;
        }
        sums[r][sub] = s;
    }
    __syncthreads();
    if (tid < 32) {
        float run = 0.f;
        for (int s = 0; s < 64; ++s) {
            float t = sums[tid][s];
            sums[tid][s] = run;
            run += t;
        }
    }
    __syncthreads();

    for (int c = 0; c < 8; ++c) {
        int tl0 = sg * 32;
        float run = sums[r][c * 8 + sg];
        const float* pf = iF + base + c * 256 + tl0;
        const _Float16* pm = mag + base + c * 256 + tl0;
        for (int i = 0; i < 32; ++i) {
            run += pf[i];
            float m = (float)pm[i];
            float sn, cs;
            __sincosf(run, &sn, &cs);   // |run| < ~200 rad; f32 reduce err ~1e-5
            ta[tl0 + i][r] = (_Float16)(m * cs);
            tb[tl0 + i][r] = (_Float16)(m * sn);
        }
        __syncthreads();
        size_t mrow = (size_t)b * T_ + c * 256 + tid;
        if (kt < 16) {
            _Float16* dstA = specT + mrow * KSPEC + kt * 32;
            _Float16* dstB = specT + mrow * KSPEC + 528 + kt * 32;
            *(h8*)(dstA + 0)  = *(const h8*)&ta[tid][0];
            *(h8*)(dstA + 8)  = *(const h8*)&ta[tid][8];
            *(h8*)(dstA + 16) = *(const h8*)&ta[tid][16];
            *(h8*)(dstA + 24) = *(const h8*)&ta[tid][24];
            *(h8*)(dstB + 0)  = *(const h8*)&tb[tid][0];
            *(h8*)(dstB + 8)  = *(const h8*)&tb[tid][8];
            *(h8*)(dstB + 16) = *(const h8*)&tb[tid][16];
            *(h8*)(dstB + 24) = *(const h8*)&tb[tid][24];
        } else {
            specT[mrow * KSPEC + 512] = ta[tid][0];
        }
        __syncthreads();
    }
}

// ---------------------------------------------------------------------------
// GEMM2 (iDFT): frames[m][j] = sum_r specT[m][r] * basisT[j][r], K=1056.
// 32x32x16 MFMA, XOR LDS, XCD swizzle. Output f16.
// ---------------------------------------------------------------------------
__global__ __launch_bounds__(256) void k_gemm_idft(
    const _Float16* __restrict__ specT, const _Float16* __restrict__ basisT,
    _Float16* __restrict__ frames) {
    __shared__ _Float16 sA[128 * 32];
    __shared__ _Float16 sB[128 * 32];
    const int tid = threadIdx.x;
    const int lane = tid & 63;
    const int wv = tid >> 6;
    const int wr = wv >> 1, wc = wv & 1;
    const int h = lane >> 5, r5 = lane & 31;
    const int L = blockIdx.x;
    const int xcd = L & 7;
    const int idx = L >> 3;
    const int j_tile = idx & 7;
    const int m_tile = (idx >> 3) * 8 + xcd;
    const int j0 = j_tile * 128;
    const int m0 = m_tile * 128;

    const int cid0 = wv * 128 + lane, cid1 = cid0 + 64;
    const int ar0 = cid0 >> 2, g0 = (cid0 & 3) ^ xorf(ar0);
    const int ar1 = cid1 >> 2, g1 = (cid1 & 3) ^ xorf(ar1);
    const _Float16* gA0 = specT + (size_t)(m0 + ar0) * KSPEC + g0 * 8;
    const _Float16* gA1 = specT + (size_t)(m0 + ar1) * KSPEC + g1 * 8;
    const _Float16* gB0 = basisT + (size_t)(j0 + ar0) * KSPEC + g0 * 8;
    const _Float16* gB1 = basisT + (size_t)(j0 + ar1) * KSPEC + g1 * 8;
    _Float16* dA = &sA[wv * 1024];
    _Float16* dB = &sB[wv * 1024];

    const int xv = xorf(r5);
    int offA[2][2], offB[2][2];
    #pragma unroll
    for (int mt = 0; mt < 2; ++mt)
        #pragma unroll
        for (int s = 0; s < 2; ++s) {
            offA[mt][s] = (wr * 64 + mt * 32 + r5) * 32 + (((s << 1) | h) ^ xv) * 8;
            offB[mt][s] = (wc * 64 + mt * 32 + r5) * 32 + (((s << 1) | h) ^ xv) * 8;
        }

    fv16 acc[2][2];
    fv16 zero = {0,0,0,0,0,0,0,0,0,0,0,0,0,0,0,0};
    #pragma unroll
    for (int i = 0; i < 2; ++i)
        #pragma unroll
        for (int j = 0; j < 2; ++j) acc[i][j] = zero;

    for (int k0 = 0; k0 < KSPEC; k0 += 32) {
        GLOAD_LDS16(gA0 + k0, dA);
        GLOAD_LDS16(gA1 + k0, dA + 512);
        GLOAD_LDS16(gB0 + k0, dB);
        GLOAD_LDS16(gB1 + k0, dB + 512);
        __syncthreads();
        h8 af[2][2], bf[2][2];
        #pragma unroll
        for (int mt = 0; mt < 2; ++mt)
            #pragma unroll
            for (int s = 0; s < 2; ++s) {
                af[mt][s] = *(const h8*)&sA[offA[mt][s]];
                bf[mt][s] = *(const h8*)&sB[offB[mt][s]];
            }
        #pragma unroll
        for (int mt = 0; mt < 2; ++mt)
            #pragma unroll
            for (int nt = 0; nt < 2; ++nt)
                #pragma unroll
                for (int s = 0; s < 2; ++s)
                    acc[mt][nt] = __builtin_amdgcn_mfma_f32_32x32x16_f16(
                        af[mt][s], bf[nt][s], acc[mt][nt], 0, 0, 0);
        __syncthreads();
    }

    #pragma unroll
    for (int mt = 0; mt < 2; ++mt)
        #pragma unroll
        for (int nt = 0; nt < 2; ++nt) {
            int col = j0 + wc * 64 + nt * 32 + r5;
            #pragma unroll
            for (int reg = 0; reg < 16; ++reg) {
                int rl = (reg & 3) + 8 * (reg >> 2) + 4 * h;
                int m = m0 + wr * 64 + mt * 32 + rl;
                frames[((size_t)m << 10) + col] = (_Float16)acc[mt][nt][reg];
            }
        }
}

// ---------------------------------------------------------------------------
// OLA gather + envelope divide + clip
// ---------------------------------------------------------------------------
__global__ void k_ola(const _Float16* __restrict__ frames, float* __restrict__ out) {
    const int s_out = blockIdx.x * 256 + threadIdx.x;
    const int b = blockIdx.y;
    const int s = s_out + NFFT / 2;
    int t_lo = (s - (NFFT - HOP)) >> 8;
    if (t_lo < 0) t_lo = 0;
    int t_hi = s >> 8;
    if (t_hi > T_ - 1) t_hi = T_ - 1;
    float acc = 0.0f, env = 0.0f;
    for (int t = t_lo; t <= t_hi; ++t) {
        int j = s - (t << 8);
        acc += (float)frames[((size_t)(b * T_ + t) << 10) + j];
        float w = 0.5f * (1.0f - __cosf((float)j * (TWO_PI_F / NFFT)));
        env += w * w;
    }
    float r = acc / env;
    r = fminf(fmaxf(r, -1.0f), 1.0f);
    out[(size_t)b * OUT_LEN + s_out] = r;
}

// ---------------------------------------------------------------------------
extern "C" void kernel_launch(void* const* d_in, const int* in_sizes, int n_in,
                              void* d_out, int out_size, void* d_ws, size_t ws_size,
                              hipStream_t stream) {
    const float* x  = (const float*)d_in[0];
    const float* Wm = (const float*)d_in[1];
    const float* bm = (const float*)d_in[2];
    const float* Wp = (const float*)d_in[3];
    const float* bp = (const float*)d_in[4];
    float* out = (float*)d_out;

    char* ws = (char*)d_ws;
    const size_t OFF_MAG   = 0;                        // 640*32768*2   = 41,943,040
    const size_t OFF_PH    = 41943040;                 // 640*32768*4   = 83,886,080
    const size_t OFF_XH    = 125829120;                // 67,108,864
    const size_t OFF_XL    = 192937984;                // 67,108,864
    const size_t OFF_WH    = 260046848;                //  2,621,440
    const size_t OFF_WL    = 262668288;                //  2,621,440
    const size_t OFF_BIAS  = 265289728;                //  5,120
    const size_t OFF_BASIS = 265294848;                //  2,162,688
    // Aliases: specT -> OFF_XH (xT dead after phase gemm), frames -> OFF_MAG

    _Float16* bufmag = (_Float16*)(ws + OFF_MAG);
    float*    bufph  = (float*)(ws + OFF_PH);
    _Float16* xh     = (_Float16*)(ws + OFF_XH);
    _Float16* xl     = (_Float16*)(ws + OFF_XL);
    _Float16* Wh     = (_Float16*)(ws + OFF_WH);
    _Float16* Wl     = (_Float16*)(ws + OFF_WL);
    float*    biasp  = (float*)(ws + OFF_BIAS);
    _Float16* basisT = (_Float16*)(ws + OFF_BASIS);
    _Float16* specT  = (_Float16*)(ws + OFF_XH);
    _Float16* frames = (_Float16*)(ws + OFF_MAG);

    k_convert_x<<<dim3(DIM / 64, T_ / 64, B_), 256, 0, stream>>>(x, xh, xl);
    k_pack_w<<<dim3(NROWS * DIM / 256), 256, 0, stream>>>(Wm, Wp, Wh, Wl);
    k_pack_bias<<<dim3((NROWS + 255) / 256), 256, 0, stream>>>(bm, bp, biasp);
    k_basisT<<<dim3((NFFT * KSPEC + 255) / 256), 256, 0, stream>>>(basisT);

    k_gemm_mag<<<dim3(5 * (M_TOT / 128)), 256, 0, stream>>>(Wh, xh, biasp, bufmag);
    k_gemm_phase<<<dim3(5 * (M_TOT / 128)), 256, 0, stream>>>(Wh, Wl, xh, xl, biasp, bufph);
    k_scan<<<dim3(17, B_), 256, 0, stream>>>(bufmag, bufph, specT);
    k_gemm_idft<<<dim3(8 * (M_TOT / 128)), 256, 0, stream>>>(specT, basisT, frames);
    k_ola<<<dim3(OUT_LEN / 256, B_), 256, 0, stream>>>(frames, out);
}